// Round 5
// baseline (201.779 us; speedup 1.0000x reference)
//
#include <hip/hip_runtime.h>
#include <math.h>

#define NN 4096
#define DD 256
#define HH 4
#define SPLIT 8
#define BM 32
#define BK 64

typedef short short8 __attribute__((ext_vector_type(8)));
typedef float float4v __attribute__((ext_vector_type(4)));

__device__ __forceinline__ unsigned short f2bf(float f) {
  unsigned u = __float_as_uint(f);
  u += 0x7FFF + ((u >> 16) & 1);   // RNE
  return (unsigned short)(u >> 16);
}
__device__ __forceinline__ unsigned int f2bf_pk(float a, float b) {
  unsigned ua = __float_as_uint(a); ua += 0x7FFF + ((ua >> 16) & 1);
  unsigned ub = __float_as_uint(b); ub += 0x7FFF + ((ub >> 16) & 1);
  return __builtin_amdgcn_perm(ub, ua, 0x07060302);
}

// ---------------- zero hp (atomic fallback only) ----------------
__global__ void k_zero(float* __restrict__ hp) {
  int idx = blockIdx.x * 256 + threadIdx.x;
  ((float4*)hp)[idx] = make_float4(0.f, 0.f, 0.f, 0.f);
}

// ======= fused: h=x*cw+cb -> hbfT (transposed bf16), s1/s2/s2e per node =======
// grid 64, block 256: block handles 64 nodes; thread t: node jj=t>>2, d-slice (t&3)*64
__global__ __launch_bounds__(256) void k_pre(
    const float* __restrict__ x, const float* __restrict__ a,
    const float* __restrict__ cwp, const float* __restrict__ cbp,
    unsigned short* __restrict__ hbfT, float* __restrict__ s1,
    float* __restrict__ s2, float* __restrict__ s2e) {
  __shared__ unsigned short sh[64 * 273];   // [jj][d], stride 273 (~34 KB)
  const int tid = threadIdx.x;
  const int j0 = blockIdx.x * 64;
  const int jj = tid >> 2, qd = (tid & 3) * 64;
  const float cw = cwp[0], cb = cbp[0];
  float p1[HH] = {0.f, 0.f, 0.f, 0.f}, p2[HH] = {0.f, 0.f, 0.f, 0.f};
#pragma unroll
  for (int k = 0; k < 16; k++) {
    const int d = qd + k * 4;
    const float4 v = *(const float4*)(x + (size_t)(j0 + jj) * DD + d);
    const float h0 = v.x * cw + cb, h1 = v.y * cw + cb;
    const float h2 = v.z * cw + cb, h3 = v.w * cw + cb;
    sh[jj * 273 + d + 0] = f2bf(h0);
    sh[jj * 273 + d + 1] = f2bf(h1);
    sh[jj * 273 + d + 2] = f2bf(h2);
    sh[jj * 273 + d + 3] = f2bf(h3);
#pragma unroll
    for (int h = 0; h < HH; h++) {
      const float4 a1 = *(const float4*)(a + h * 512 + d);
      const float4 a2 = *(const float4*)(a + h * 512 + 256 + d);
      p1[h] += h0 * a1.x + h1 * a1.y + h2 * a1.z + h3 * a1.w;
      p2[h] += h0 * a2.x + h1 * a2.y + h2 * a2.z + h3 * a2.w;
    }
  }
#pragma unroll
  for (int off = 1; off <= 2; off <<= 1) {
#pragma unroll
    for (int h = 0; h < HH; h++) {
      p1[h] += __shfl_xor(p1[h], off);
      p2[h] += __shfl_xor(p2[h], off);
    }
  }
  if ((tid & 3) == 0) {
#pragma unroll
    for (int h = 0; h < HH; h++) {
      s1[h * NN + j0 + jj] = p1[h];
      s2[h * NN + j0 + jj] = p2[h];
      s2e[h * NN + j0 + jj] = __expf(p2[h]);
    }
  }
  __syncthreads();
  // transposed write: 16 lanes cover one d-row's 64 j's (coalesced 128B)
  const int dgrp = tid >> 4;        // 0..15
  const int jc = (tid & 15) * 4;    // j-chunk of 4
#pragma unroll
  for (int p = 0; p < 16; p++) {
    const int d = p * 16 + dgrp;
    const unsigned l0 = sh[(jc + 0) * 273 + d];
    const unsigned l1 = sh[(jc + 1) * 273 + d];
    const unsigned l2 = sh[(jc + 2) * 273 + d];
    const unsigned l3 = sh[(jc + 3) * 273 + d];
    uint2 val;
    val.x = l0 | (l1 << 16);
    val.y = l2 | (l3 << 16);
    *(uint2*)(hbfT + (size_t)d * NN + j0 + jc) = val;
  }
}

// ---------------- M[h] = max_j s2[h][j] ----------------
__global__ void k_maxs2(const float* __restrict__ s2, float* __restrict__ M) {
  const int h = blockIdx.x;
  float m = -1e30f;
  for (int j = threadIdx.x; j < NN; j += 256) m = fmaxf(m, s2[h * NN + j]);
#pragma unroll
  for (int off = 32; off; off >>= 1) m = fmaxf(m, __shfl_xor(m, off));
  __shared__ float red[4];
  const int lane = threadIdx.x & 63, wave = threadIdx.x >> 6;
  if (lane == 0) red[wave] = m;
  __syncthreads();
  if (threadIdx.x == 0)
    M[h] = fmaxf(fmaxf(red[0], red[1]), fmaxf(red[2], red[3]));
}

// ======= fused Z + W, P kept in REGISTERS (packed bf16), separable exp =======
__global__ __launch_bounds__(256) void k_zw(
    const int* __restrict__ adj, const float* __restrict__ s1g,
    const float* __restrict__ s2e, const float* __restrict__ Mb,
    unsigned short* __restrict__ Wm) {
  __shared__ float red[4][HH];
  __shared__ float sZi[HH];

  const int i = blockIdx.x;
  const int tid = threadIdx.x;
  float Rp[HH], RpRB[HH], Cc[HH], z[HH];
#pragma unroll
  for (int h = 0; h < HH; h++) {
    const float s1v = s1g[h * NN + i];
    const float t = s1v + Mb[h];
    const float B = t > 0.f ? t : __expf(t) - 1.f;
    Rp[h] = __expf(s1v);
    RpRB[h] = __expf(s1v - B);
    Cc[h] = __expf(-1.f - B);
    z[h] = 0.f;
  }
  unsigned int P[4][HH][2];   // 32 VGPRs of packed bf16 probabilities
  const int4* arow = (const int4*)(adj + (size_t)i * NN);
#pragma unroll
  for (int k = 0; k < 4; k++) {
    const int j4 = tid + k * 256;
    const int4 av = arow[j4];
    const bool m0 = av.x > 0, m1 = av.y > 0, m2 = av.z > 0, m3 = av.w > 0;
#pragma unroll
    for (int h = 0; h < HH; h++) {
      const float4 E = *(const float4*)(s2e + h * NN + j4 * 4);
      float u, p0, p1, p2, p3;
      u = Rp[h] * E.x; p0 = u > 1.f ? RpRB[h] * E.x : Cc[h] * __expf(u);
      u = Rp[h] * E.y; p1 = u > 1.f ? RpRB[h] * E.y : Cc[h] * __expf(u);
      u = Rp[h] * E.z; p2 = u > 1.f ? RpRB[h] * E.z : Cc[h] * __expf(u);
      u = Rp[h] * E.w; p3 = u > 1.f ? RpRB[h] * E.w : Cc[h] * __expf(u);
      p0 = m0 ? p0 : 0.f; p1 = m1 ? p1 : 0.f;
      p2 = m2 ? p2 : 0.f; p3 = m3 ? p3 : 0.f;
      z[h] += (p0 + p1) + (p2 + p3);
      P[k][h][0] = f2bf_pk(p0, p1);
      P[k][h][1] = f2bf_pk(p2, p3);
    }
  }
#pragma unroll
  for (int h = 0; h < HH; h++) {
#pragma unroll
    for (int off = 32; off; off >>= 1) z[h] += __shfl_xor(z[h], off);
  }
  const int lane = tid & 63, wave = tid >> 6;
  if (lane == 0) {
#pragma unroll
    for (int h = 0; h < HH; h++) red[wave][h] = z[h];
  }
  __syncthreads();
  if (tid < HH) {
    const float zt = red[0][tid] + red[1][tid] + red[2][tid] + red[3][tid];
    sZi[tid] = zt > 0.f ? 0.25f / zt : 0.f;
  }
  __syncthreads();
  float Zi[HH];
#pragma unroll
  for (int h = 0; h < HH; h++) Zi[h] = sZi[h];

  unsigned int* wrow = (unsigned int*)(Wm + (size_t)i * NN);
#pragma unroll
  for (int k = 0; k < 4; k++) {
    const int j4 = tid + k * 256;
    float w0 = 0.f, w1 = 0.f, w2 = 0.f, w3 = 0.f;
#pragma unroll
    for (int h = 0; h < HH; h++) {
      const unsigned int pa = P[k][h][0];
      const unsigned int pb = P[k][h][1];
      w0 += __uint_as_float(pa << 16) * Zi[h];
      w1 += __uint_as_float(pa & 0xffff0000u) * Zi[h];
      w2 += __uint_as_float(pb << 16) * Zi[h];
      w3 += __uint_as_float(pb & 0xffff0000u) * Zi[h];
    }
    wrow[j4 * 2] = f2bf_pk(w0, w1);
    wrow[j4 * 2 + 1] = f2bf_pk(w2, w3);
  }
}

// ======= barrier-free MFMA GEMM, BM=32 -> 1024 blocks (4/CU) =======
__global__ __launch_bounds__(256) void k_gemm(
    const unsigned short* __restrict__ Wm, const unsigned short* __restrict__ hbfT,
    float* __restrict__ hpOut, int useSplit) {
  const int tid = threadIdx.x;
  const int w = tid >> 6, lane = tid & 63;
  const int m16 = lane & 15, q = lane >> 4;
  const int rb = blockIdx.x >> 3, sp = blockIdx.x & 7;
  const int i0 = rb * BM;
  const int jlo = sp * (NN / SPLIT);

  const unsigned short* Ab = Wm + (size_t)(i0 + m16) * NN + jlo + q * 8;
  const unsigned short* Bbp = hbfT + (size_t)(w * 64 + m16) * NN + jlo + q * 8;

  float4v acc[2][4];
#pragma unroll
  for (int a = 0; a < 2; a++)
#pragma unroll
    for (int b = 0; b < 4; b++) acc[a][b] = (float4v)0.f;

#pragma unroll 2
  for (int kt = 0; kt < (NN / SPLIT) / BK; kt++) {
    short8 aF[2][2], bF[2][4];
#pragma unroll
    for (int ks = 0; ks < 2; ks++)
#pragma unroll
      for (int it = 0; it < 2; it++)
        aF[ks][it] = *(const short8*)(Ab + (size_t)it * 16 * NN + kt * BK + ks * 32);
#pragma unroll
    for (int ks = 0; ks < 2; ks++)
#pragma unroll
      for (int dt = 0; dt < 4; dt++)
        bF[ks][dt] = *(const short8*)(Bbp + (size_t)dt * 16 * NN + kt * BK + ks * 32);
#pragma unroll
    for (int ks = 0; ks < 2; ks++)
#pragma unroll
      for (int it = 0; it < 2; it++)
#pragma unroll
        for (int dt = 0; dt < 4; dt++)
          acc[it][dt] = __builtin_amdgcn_mfma_f32_16x16x32_bf16(aF[ks][it], bF[ks][dt], acc[it][dt], 0, 0, 0);
  }

  if (useSplit) {
    float* base = hpOut + (size_t)sp * NN * DD;
#pragma unroll
    for (int it = 0; it < 2; it++)
#pragma unroll
      for (int dt = 0; dt < 4; dt++) {
        const int d = w * 64 + dt * 16 + m16;
#pragma unroll
        for (int rg = 0; rg < 4; rg++) {
          const int i = i0 + it * 16 + q * 4 + rg;
          base[(size_t)i * DD + d] = acc[it][dt][rg];
        }
      }
  } else {
#pragma unroll
    for (int it = 0; it < 2; it++)
#pragma unroll
      for (int dt = 0; dt < 4; dt++) {
        const int d = w * 64 + dt * 16 + m16;
#pragma unroll
        for (int rg = 0; rg < 4; rg++) {
          const int i = i0 + it * 16 + q * 4 + rg;
          atomicAdd(&hpOut[(size_t)i * DD + d], acc[it][dt][rg]);
        }
      }
  }
}

// ---------------- epilogue: float4 split reads ----------------
__global__ void k_epi(const float* __restrict__ hp, int nsplit,
                      const float* __restrict__ x, const float* __restrict__ cwp,
                      const float* __restrict__ cbp, const float* __restrict__ bias,
                      float* __restrict__ out) {
  const int lane = threadIdx.x & 63, wave = threadIdx.x >> 6;
  const int i = blockIdx.x * 4 + wave;
  const float cw = cwp[0], cb = cbp[0];
  const int d4 = lane * 4;
  float4 pv = make_float4(0.f, 0.f, 0.f, 0.f);
  for (int s = 0; s < nsplit; s++) {
    const float4 t = *(const float4*)(hp + (size_t)s * NN * DD + (size_t)i * DD + d4);
    pv.x += t.x; pv.y += t.y; pv.z += t.z; pv.w += t.w;
  }
  const float4 xv = *(const float4*)(x + (size_t)i * DD + d4);
  float4 v;
  v.x = 0.5f * pv.x + 0.5f * (xv.x * cw + cb);
  v.y = 0.5f * pv.y + 0.5f * (xv.y * cw + cb);
  v.z = 0.5f * pv.z + 0.5f * (xv.z * cw + cb);
  v.w = 0.5f * pv.w + 0.5f * (xv.w * cw + cb);
  v.x = v.x > 0.f ? v.x : expm1f(v.x);
  v.y = v.y > 0.f ? v.y : expm1f(v.y);
  v.z = v.z > 0.f ? v.z : expm1f(v.z);
  v.w = v.w > 0.f ? v.w : expm1f(v.w);
  float ss = v.x * v.x + v.y * v.y + v.z * v.z + v.w * v.w;
#pragma unroll
  for (int off = 32; off; off >>= 1) ss += __shfl_xor(ss, off);
  const float inv = 1.f / fmaxf(sqrtf(ss), 1e-12f);
  const float4 bv = *(const float4*)(bias + d4);
  float4 o;
  o.x = v.x * inv + bv.x;
  o.y = v.y * inv + bv.y;
  o.z = v.z * inv + bv.z;
  o.w = v.w * inv + bv.w;
  *(float4*)(out + (size_t)i * DD + d4) = o;
}

extern "C" void kernel_launch(void* const* d_in, const int* in_sizes, int n_in,
                              void* d_out, int out_size, void* d_ws, size_t ws_size,
                              hipStream_t stream) {
  const float* x = (const float*)d_in[0];
  const int* adj = (const int*)d_in[1];
  const float* cw = (const float*)d_in[2];
  const float* cb = (const float*)d_in[3];
  const float* a = (const float*)d_in[4];
  const float* bias = (const float*)d_in[5];
  float* out = (float*)d_out;
  float* ws = (float*)d_ws;

  // layout (float units): s1 | s2 | s2e | Mb | hbfT | Wm | hp
  float* s1 = ws;
  float* s2 = ws + 16384;
  float* s2e = ws + 32768;
  float* Mb = ws + 49152;
  unsigned short* hbfT = (unsigned short*)(ws + 49408);
  unsigned short* Wm = (unsigned short*)(ws + 49408 + 524288);
  float* hp = ws + 49408 + 524288 + 8388608;

  const size_t needSplit = (size_t)(49408 + 524288 + 8388608 + (size_t)SPLIT * NN * DD) * 4;
  const int useSplit = (ws_size >= needSplit) ? 1 : 0;
  const int nsplit = useSplit ? SPLIT : 1;

  if (!useSplit) hipLaunchKernelGGL(k_zero, dim3(1024), dim3(256), 0, stream, hp);
  hipLaunchKernelGGL(k_pre, dim3(64), dim3(256), 0, stream, x, a, cw, cb, hbfT, s1, s2, s2e);
  hipLaunchKernelGGL(k_maxs2, dim3(HH), dim3(256), 0, stream, s2, Mb);
  hipLaunchKernelGGL(k_zw, dim3(NN), dim3(256), 0, stream, adj, s1, s2e, Mb, Wm);
  hipLaunchKernelGGL(k_gemm, dim3((NN / BM) * SPLIT), dim3(256), 0, stream, Wm, hbfT, hp, useSplit);
  hipLaunchKernelGGL(k_epi, dim3(1024), dim3(256), 0, stream, hp, nsplit, x, cw, cb, bias, out);
}